// Round 1
// 414.725 us; speedup vs baseline: 1.0002x; 1.0002x over previous
//
#include <hip/hip_runtime.h>
#include <hip/hip_bf16.h>

// Problem: B=16, N=2048, F=128, HID=32, FC=512, C=10
// softmax over size-1 cluster axis => S == 1, so
//   Xp[b,h] = sum_n relu( (A @ (X@W1))[b,n,h] + b1[h] )
// One 268 MB pass over A. k2 v3: XWT moved into the per-wave LDS ring so the
// K-loop's only VMEM ops are the homogeneous global_load_lds stream -> one
// counted vmcnt(8), no in-order-retirement drains from L2 operand loads.

#define B_   16
#define N_   2048
#define F_   128
#define HID_ 32
#define FC_  512
#define C_   10

typedef __bf16 bf16x8 __attribute__((ext_vector_type(8)));
typedef float  f32x4  __attribute__((ext_vector_type(4)));
typedef float  floatx4 __attribute__((ext_vector_type(4)));

typedef const __attribute__((address_space(1))) void* as1_cvp;
typedef __attribute__((address_space(3))) void*       as3_vp;

__device__ static __forceinline__ void dma16(void* lds_uniform, const void* g) {
    __builtin_amdgcn_global_load_lds((as1_cvp)g, (as3_vp)lds_uniform, 16, 0, 0);
}

// ---------------------------------------------------------------------------
// Kernel 1: XWT[b][h][m] = (X[b] @ W1)[m][h] in bf16. Also zeros Xp.
// v3: 512 blocks (2 blocks/CU, was 1) -> 64 rows/block, same per-lane math.
// ---------------------------------------------------------------------------
__global__ __launch_bounds__(256) void k1_xw(
    const float* __restrict__ X, const float* __restrict__ W1,
    __bf16* __restrict__ XWT, float* __restrict__ Xp)
{
    const int tid = threadIdx.x;
    if (blockIdx.x == 0) {
        for (int i = tid; i < B_ * HID_; i += 256) Xp[i] = 0.f;
    }
    const int b   = blockIdx.x >> 5;          // 512 blocks: 32 segs per batch
    const int seg = blockIdx.x & 31;
    const int w    = tid >> 6;
    const int lane = tid & 63;
    const int r = lane & 15, q = lane >> 4;

    bf16x8 wf[2][4];
    #pragma unroll
    for (int t = 0; t < 2; ++t) {
        const int h = r + 16 * t;
        #pragma unroll
        for (int ks = 0; ks < 4; ++ks) {
            bf16x8 v;
            #pragma unroll
            for (int j = 0; j < 8; ++j) {
                const int f = ks * 32 + q * 8 + j;
                v[j] = (__bf16)W1[f * HID_ + h];
            }
            wf[t][ks] = v;
        }
    }

    const int m = seg * 64 + w * 16 + r;
    const floatx4* xrow = (const floatx4*)(X + ((size_t)(b * N_ + m)) * F_);
    f32x4 acc0 = {0.f, 0.f, 0.f, 0.f};
    f32x4 acc1 = {0.f, 0.f, 0.f, 0.f};
    #pragma unroll
    for (int ks = 0; ks < 4; ++ks) {
        floatx4 x0 = xrow[ks * 8 + q * 2];
        floatx4 x1 = xrow[ks * 8 + q * 2 + 1];
        bf16x8 bf;
        bf[0] = (__bf16)x0[0]; bf[1] = (__bf16)x0[1];
        bf[2] = (__bf16)x0[2]; bf[3] = (__bf16)x0[3];
        bf[4] = (__bf16)x1[0]; bf[5] = (__bf16)x1[1];
        bf[6] = (__bf16)x1[2]; bf[7] = (__bf16)x1[3];
        acc0 = __builtin_amdgcn_mfma_f32_16x16x32_bf16(wf[0][ks], bf, acc0, 0, 0, 0);
        acc1 = __builtin_amdgcn_mfma_f32_16x16x32_bf16(wf[1][ks], bf, acc1, 0, 0, 0);
    }
    #pragma unroll
    for (int reg = 0; reg < 4; ++reg) {
        const int h0 = q * 4 + reg;
        XWT[((size_t)(b * HID_ + h0)) * N_ + m]      = (__bf16)acc0[reg];
        XWT[((size_t)(b * HID_ + h0 + 16)) * N_ + m] = (__bf16)acc1[reg];
    }
}

// ---------------------------------------------------------------------------
// Kernel 2 (the 268 MB pass), v3: A AND XWT both DMA-staged into a
// per-wave-private LDS ring (no barrier anywhere in the K-loop).
// Grid 512 x 256. Block = 64 rows full-K; wave = 16 rows.
// K-chunks of 64 cols: A 4 KB (4 dma16) + XWT 4 KB (4 dma16) per wave.
// NBUF=2 ring (8 KB/wave/chunk -> 64 KB LDS/block, 2 blocks/CU).
// Loop: waitcnt vmcnt(8) [chunk c landed; c+1 in flight]; compute(c) all from
// LDS (lgkm only); stage(c+2) into the just-freed slot. The vmcnt queue holds
// ONLY stage DMAs -> no in-order-retirement coupling with operand loads.
// XOR swizzles: A slot s in row r holds chunk s^(r&7) (16 slots x 16B);
// XWT slot s in row h holds chunk s^(h&7) (8 slots x 16B) -> both ds_read
// patterns are bank-balanced (8 words/bank = wave64-b128 minimum).
// ---------------------------------------------------------------------------
__global__ __launch_bounds__(256, 2) void k2_axw(
    const float* __restrict__ A, const __bf16* __restrict__ XWT,
    const float* __restrict__ b1, float* __restrict__ Xp)
{
    __shared__ __align__(16) float  abuf[2][4][16 * 64];  // [buf][wave][row*64+col] 32 KB
    __shared__ __align__(16) __bf16 xbuf[2][4][32 * 64];  // [buf][wave][h*64+col]   32 KB
    __shared__ float sdata[4][HID_];

    const int tid  = threadIdx.x;
    const int w    = tid >> 6;
    const int lane = tid & 63;
    const int r = lane & 15, q = lane >> 4;
    const int rs = r & 7;

    const int b       = blockIdx.x >> 5;          // 512 blocks: 32 per batch
    const int rowBase = (blockIdx.x & 31) * 64;   // 4 waves x 16 rows
    const int row0    = rowBase + w * 16;

    const int rl = lane >> 4;     // A: row sub-index within a DMA instr (0..3)
    const int ch = lane & 15;     // A: 16B chunk slot within LDS row
    const int xh = lane >> 3;     // XWT: row sub-index within a DMA instr (0..7)
    const int xs8 = lane & 7;     // XWT: 16B chunk slot within LDS row

    f32x4 acc0 = {0.f, 0.f, 0.f, 0.f};
    f32x4 acc1 = {0.f, 0.f, 0.f, 0.f};

    auto stage = [&](int c) {
        const int t = c & 1;
        #pragma unroll
        for (int j = 0; j < 4; ++j) {                        // A: 16 rows x 64 f32
            const int rlocal = j * 4 + rl;                   // 0..15
            const int gchunk = ch ^ (rlocal & 7);            // swizzled source
            const size_t gelem = ((size_t)(b * N_ + row0 + rlocal)) * N_
                               + (size_t)c * 64 + (size_t)(gchunk * 4);
            dma16((void*)&abuf[t][w][j * 256], (const void*)(A + gelem));
        }
        #pragma unroll
        for (int j = 0; j < 4; ++j) {                        // XWT: 32 h x 64 bf16
            const int h  = j * 8 + xh;                       // 0..31
            const int gc = xs8 ^ (h & 7);                    // swizzled source
            const size_t ge = ((size_t)(b * HID_ + h)) * N_
                            + (size_t)c * 64 + (size_t)(gc * 8);
            dma16((void*)&xbuf[t][w][j * 512], (const void*)(XWT + ge));
        }
    };

    auto compute = [&](int c) {
        const int t = c & 1;
        const float*  aw = &abuf[t][w][0];
        const __bf16* xw = &xbuf[t][w][0];
        #pragma unroll
        for (int kl = 0; kl < 2; ++kl) {
            const int s0 = (kl * 8 + q * 2) ^ rs;            // A slot (even g -> g^1 pairs)
            const floatx4 u0 = *(const floatx4*)(aw + r * 64 + s0 * 4);
            const floatx4 u1 = *(const floatx4*)(aw + r * 64 + (s0 ^ 1) * 4);
            bf16x8 af;
            af[0] = (__bf16)u0[0]; af[1] = (__bf16)u0[1];
            af[2] = (__bf16)u0[2]; af[3] = (__bf16)u0[3];
            af[4] = (__bf16)u1[0]; af[5] = (__bf16)u1[1];
            af[6] = (__bf16)u1[2]; af[7] = (__bf16)u1[3];
            const int xs = (kl * 4 + q) ^ rs;                // XWT 16B slot
            const bf16x8 bf0 = *(const bf16x8*)(xw + r * 64 + xs * 8);
            const bf16x8 bf1 = *(const bf16x8*)(xw + (r + 16) * 64 + xs * 8);
            acc0 = __builtin_amdgcn_mfma_f32_16x16x32_bf16(af, bf0, acc0, 0, 0, 0);
            acc1 = __builtin_amdgcn_mfma_f32_16x16x32_bf16(af, bf1, acc1, 0, 0, 0);
        }
    };

    stage(0);
    stage(1);
    for (int c = 0; c < 32; ++c) {
        // s_waitcnt imm: vmcnt[3:0], expcnt[6:4]=7 (ignore), lgkmcnt[11:8]=15 (ignore)
        if (c < 31) __builtin_amdgcn_s_waitcnt(0x0F78);  // vmcnt(8): chunk c landed
        else        __builtin_amdgcn_s_waitcnt(0x0F70);  // vmcnt(0): drain tail
        compute(c);
        if (c + 2 < 32) stage(c + 2);                    // into just-freed slot
    }

    // Epilogue: D col(h)=r(+16), rows=q*4+reg. bias+relu after full K, then
    // sum over this wave's 16 rows; cross-wave combine in LDS; one atomic set.
    const float bias0 = b1[r], bias1 = b1[r + 16];
    float s0 = 0.f, s1 = 0.f;
    #pragma unroll
    for (int reg = 0; reg < 4; ++reg) {
        s0 += fmaxf(acc0[reg] + bias0, 0.f);
        s1 += fmaxf(acc1[reg] + bias1, 0.f);
    }
    s0 += __shfl_xor(s0, 16); s0 += __shfl_xor(s0, 32);
    s1 += __shfl_xor(s1, 16); s1 += __shfl_xor(s1, 32);

    if (lane < 16) { sdata[w][r] = s0; sdata[w][r + 16] = s1; }
    __syncthreads();
    if (tid < HID_) {
        atomicAdd(&Xp[b * HID_ + tid],
                  sdata[0][tid] + sdata[1][tid] + sdata[2][tid] + sdata[3][tid]);
    }
}

// ---------------------------------------------------------------------------
// Kernel 3: dense head per batch (unchanged — verified correct)
// ---------------------------------------------------------------------------
__global__ __launch_bounds__(256) void k3_head(
    const float* __restrict__ Xp, const float* __restrict__ Wd,
    const float* __restrict__ bd, const float* __restrict__ Wc,
    const float* __restrict__ bc, float* __restrict__ out)
{
    __shared__ float xp[HID_];
    __shared__ float hbuf[FC_];
    __shared__ float logits[C_];
    const int b = blockIdx.x;
    const int t = threadIdx.x;

    if (t < HID_) xp[t] = Xp[b * HID_ + t];
    __syncthreads();

    for (int f = t; f < FC_; f += 256) {
        float acc = bd[f];
        #pragma unroll
        for (int j = 0; j < HID_; ++j) acc += xp[j] * Wd[j * FC_ + f];
        hbuf[f] = fmaxf(acc, 0.f);
    }
    __syncthreads();

    if (t < 16 * C_) {
        const int c = t >> 4, l = t & 15;
        float acc = 0.f;
        for (int f = l; f < FC_; f += 16) acc += hbuf[f] * Wc[f * C_ + c];
        acc += __shfl_xor(acc, 8, 16);
        acc += __shfl_xor(acc, 4, 16);
        acc += __shfl_xor(acc, 2, 16);
        acc += __shfl_xor(acc, 1, 16);
        if (l == 0) logits[c] = acc + bc[c];
    }
    __syncthreads();

    if (t == 0) {
        float mx = logits[0];
        #pragma unroll
        for (int c = 1; c < C_; ++c) mx = fmaxf(mx, logits[c]);
        float e[C_]; float sum = 0.f;
        #pragma unroll
        for (int c = 0; c < C_; ++c) { e[c] = expf(logits[c] - mx); sum += e[c]; }
        const float inv = 1.f / sum;
        #pragma unroll
        for (int c = 0; c < C_; ++c) out[b * C_ + c] = e[c] * inv;
    }
}

// ---------------------------------------------------------------------------
extern "C" void kernel_launch(void* const* d_in, const int* in_sizes, int n_in,
                              void* d_out, int out_size, void* d_ws, size_t ws_size,
                              hipStream_t stream) {
    const float* filtre = (const float*)d_in[0];
    const float* X      = (const float*)d_in[1];
    // d_in[2] node_indicator: unused by the reference
    const float* W1     = (const float*)d_in[3];
    const float* b1     = (const float*)d_in[4];
    // d_in[5] Ws: dead code (softmax over size-1 axis == 1)
    const float* Wd     = (const float*)d_in[6];
    const float* bd     = (const float*)d_in[7];
    const float* Wc     = (const float*)d_in[8];
    const float* bc     = (const float*)d_in[9];
    float* out = (float*)d_out;

    __bf16* XWT = (__bf16*)d_ws;                                   // 2 MB
    float*  Xp  = (float*)((char*)d_ws + (size_t)B_ * HID_ * N_ * sizeof(__bf16));

    k1_xw <<<512, 256, 0, stream>>>(X, W1, XWT, Xp);
    k2_axw<<<512, 256, 0, stream>>>(filtre, XWT, b1, Xp);
    k3_head<<<B_,  256, 0, stream>>>(Xp, Wd, bd, Wc, bc, out);
}